// Round 2
// baseline (243.643 us; speedup 1.0000x reference)
//
#include <hip/hip_runtime.h>
#include <hip/hip_bf16.h>
#include <math.h>

#define NB 32768      // batch rows per node
#define CD 128        // input channels
#define NNODES 6
#define OUTW 1536     // 6 * 256 output features per batch row

typedef __attribute__((ext_vector_type(8))) short short8;
typedef __attribute__((ext_vector_type(4))) float f32x4;

static __device__ __forceinline__ short f2bf(float f) {
    union { float f; unsigned u; } v; v.f = f;
    unsigned r = v.u + 0x7FFFu + ((v.u >> 16) & 1u);   // round-nearest-even
    return (short)(r >> 16);
}

// LDS-free, barrier-free: each lane produces its MFMA A-fragments directly
// from global loads (row = lane&15, k-chunk = lane>>4), aggregates computed
// in-register. No cross-thread communication anywhere -> race-free by
// construction. Wave owns 16 output cols; block = 4 waves = 64 cols;
// 4 blocks per 16-row group cover all 256 cols.
__global__ __launch_bounds__(256, 3)
void sage_nolds(const float* __restrict__ x, const float* __restrict__ Wl,
                const float* __restrict__ Wr, const float* __restrict__ bias,
                float* __restrict__ out) {
    const int t = threadIdx.x;
    const int lane = t & 63;
    const int wv = t >> 6;        // wave 0..3
    const int lo = lane & 15;     // A-row / B-col / D-col index
    const int hi = lane >> 4;     // k-subchunk / D-row-group index
    const int rowGroup = blockIdx.x >> 2;
    const int oBlk = blockIdx.x & 3;
    const int o = oBlk * 64 + wv * 16 + lo;    // this lane's output column

    // B fragments: bfrag[s][e] = Wcat[o][s*32 + hi*8 + e]
    // Wcat[o][k] = k<128 ? Wl[o][k] : Wr[o][k-128]  (B^T convention, validated R1)
    short8 bfrag[8];
    #pragma unroll
    for (int s = 0; s < 8; ++s) {
        const int kb = s * 32 + hi * 8;
        const float* src = (kb < 128) ? (Wl + o * CD + kb)
                                      : (Wr + o * CD + (kb - 128));
        f32x4 f0 = *(const f32x4*)src;
        f32x4 f1 = *(const f32x4*)(src + 4);
        short8 pk;
        #pragma unroll
        for (int j = 0; j < 4; ++j) { pk[j] = f2bf(f0[j]); pk[4 + j] = f2bf(f1[j]); }
        bfrag[s] = pk;
    }
    const float bias_v = bias[o];

    const size_t row = (size_t)rowGroup * 16 + lo;   // batch row this lane supplies

    f32x4 acc[NNODES];
    #pragma unroll
    for (int n = 0; n < NNODES; ++n) acc[n] = (f32x4){0.f, 0.f, 0.f, 0.f};

    #pragma unroll
    for (int m = 0; m < 4; ++m) {                    // 32-col chunk of the 128 channels
        const int c0 = m * 32 + hi * 8;
        const float* pbase = x + row * CD + c0;
        float xf[NNODES][8];
        #pragma unroll
        for (int s = 0; s < NNODES; ++s) {
            const float* p = pbase + (size_t)s * (NB * CD);
            f32x4 a = *(const f32x4*)p;
            f32x4 c = *(const f32x4*)(p + 4);
            #pragma unroll
            for (int j = 0; j < 4; ++j) { xf[s][j] = a[j]; xf[s][4 + j] = c[j]; }
        }
        // aggregates: N(0)=all-{0} /5, N(1)=all-{1} /5,
        // N(2)=N(5)={0,1,3,4} /4, N(3)=N(4)={0,1,2,5} /4
        short8 g0b, g1b, g25b, g34b, xb[NNODES];
        #pragma unroll
        for (int j = 0; j < 8; ++j) {
            const float T = xf[0][j] + xf[1][j] + xf[2][j] + xf[3][j] + xf[4][j] + xf[5][j];
            g0b[j]  = f2bf((T - xf[0][j]) * 0.2f);
            g1b[j]  = f2bf((T - xf[1][j]) * 0.2f);
            g25b[j] = f2bf((T - xf[2][j] - xf[5][j]) * 0.25f);
            g34b[j] = f2bf((T - xf[3][j] - xf[4][j]) * 0.25f);
        }
        #pragma unroll
        for (int s = 0; s < NNODES; ++s)
            #pragma unroll
            for (int j = 0; j < 8; ++j) xb[s][j] = f2bf(xf[s][j]);

        // agg half: k-step = m  (Wcat cols 0..127 = Wl)
        acc[0] = __builtin_amdgcn_mfma_f32_16x16x32_bf16(g0b,  bfrag[m], acc[0], 0, 0, 0);
        acc[1] = __builtin_amdgcn_mfma_f32_16x16x32_bf16(g1b,  bfrag[m], acc[1], 0, 0, 0);
        acc[2] = __builtin_amdgcn_mfma_f32_16x16x32_bf16(g25b, bfrag[m], acc[2], 0, 0, 0);
        acc[3] = __builtin_amdgcn_mfma_f32_16x16x32_bf16(g34b, bfrag[m], acc[3], 0, 0, 0);
        acc[4] = __builtin_amdgcn_mfma_f32_16x16x32_bf16(g34b, bfrag[m], acc[4], 0, 0, 0);
        acc[5] = __builtin_amdgcn_mfma_f32_16x16x32_bf16(g25b, bfrag[m], acc[5], 0, 0, 0);
        // x half: k-step = m+4 (Wcat cols 128..255 = Wr)
        #pragma unroll
        for (int n = 0; n < NNODES; ++n)
            acc[n] = __builtin_amdgcn_mfma_f32_16x16x32_bf16(xb[n], bfrag[m + 4], acc[n], 0, 0, 0);
    }

    // D-frag: col = lane&15 (=o), row = hi*4 + j   [m89-verified, validated R1]
    const size_t row0 = (size_t)rowGroup * 16;
    #pragma unroll
    for (int n = 0; n < NNODES; ++n) {
        #pragma unroll
        for (int j = 0; j < 4; ++j) {
            const float v = acc[n][j] + bias_v;
            const float g = 0.5f * v * (1.0f + erff(v * 0.70710678118654752f));
            out[(row0 + (size_t)hi * 4 + j) * OUTW + n * 256 + o] = g;
        }
    }
}

extern "C" void kernel_launch(void* const* d_in, const int* in_sizes, int n_in,
                              void* d_out, int out_size, void* d_ws, size_t ws_size,
                              hipStream_t stream) {
    const float* x  = (const float*)d_in[0];
    const float* Wl = (const float*)d_in[1];
    const float* Wr = (const float*)d_in[2];
    const float* b  = (const float*)d_in[3];
    float* out = (float*)d_out;
    // (NB/16) row groups x 4 o-blocks
    sage_nolds<<<dim3((NB / 16) * 4), dim3(256), 0, stream>>>(x, Wl, Wr, b, out);
}

// Round 3
// 123.595 us; speedup vs baseline: 1.9713x; 1.9713x over previous
//
#include <hip/hip_runtime.h>
#include <hip/hip_bf16.h>

#define NB 32768      // batch rows per node
#define CD 128        // input channels
#define NNODES 6
#define OUTW 1536     // 6*256 output cols
#define KW 256        // concat K per node GEMM

typedef __attribute__((ext_vector_type(8))) short short8;
typedef __attribute__((ext_vector_type(4))) float f32x4;

// hardware f32->bf16 (RNE); compiler emits gfx950 cvt (m240: casts beat hand-asm)
static __device__ __forceinline__ short f2bf(float f) {
    union { __bf16 b; short s; } u;
    u.b = (__bf16)f;
    return u.s;
}

// ---- prologue: Wcat[o][k] bf16 in d_ws; k<128 -> Wl[o][k], else Wr[o][k-128]
__global__ void prep_w(const float* __restrict__ Wl, const float* __restrict__ Wr,
                       short* __restrict__ Wb) {
    const int i = (blockIdx.x * 256 + threadIdx.x) * 8;   // short8 chunk
    const int o = i >> 8;
    const int k = i & 255;
    const float* src = (k < 128) ? (Wl + o * CD + k) : (Wr + o * CD + (k - 128));
    f32x4 a = *(const f32x4*)src;
    f32x4 b = *(const f32x4*)(src + 4);
    short8 p;
    #pragma unroll
    for (int j = 0; j < 4; ++j) { p[j] = f2bf(a[j]); p[4 + j] = f2bf(b[j]); }
    *(short8*)(Wb + i) = p;
}

// ---- fused SAGE: LDS-free direct-fragment MFMA. Wave = 16 rows x 64 cols
// (4 o-strips) x 6 nodes; block's 4 waves cover all 256 cols of the same
// 16-row group (A-prep redundancy 4x, x re-reads L1-hit).
__global__ __launch_bounds__(256, 2)
void sage_v3(const float* __restrict__ x, const short* __restrict__ Wb,
             const float* __restrict__ bias, float* __restrict__ out) {
    const int t = threadIdx.x;
    const int lane = t & 63;
    const int wv = t >> 6;
    const int lo = lane & 15;     // A-row / B-col / D-col
    const int hi = lane >> 4;     // k-subchunk / D-row-group
    const int obase = wv * 64;
    const size_t row = (size_t)blockIdx.x * 16 + lo;

    float bias_v[4];
    #pragma unroll
    for (int i = 0; i < 4; ++i) bias_v[i] = bias[obase + i * 16 + lo];

    f32x4 acc[NNODES][4];
    #pragma unroll
    for (int n = 0; n < NNODES; ++n)
        #pragma unroll
        for (int i = 0; i < 4; ++i) acc[n][i] = (f32x4){0.f, 0.f, 0.f, 0.f};

    #pragma unroll
    for (int m = 0; m < 4; ++m) {              // 32-channel chunk
        const float* pb = x + row * CD + m * 32 + hi * 8;
        float xf[NNODES][8];
        #pragma unroll
        for (int s = 0; s < NNODES; ++s) {
            f32x4 a = *(const f32x4*)(pb + (size_t)s * (NB * CD));
            f32x4 c = *(const f32x4*)(pb + (size_t)s * (NB * CD) + 4);
            #pragma unroll
            for (int j = 0; j < 4; ++j) { xf[s][j] = a[j]; xf[s][4 + j] = c[j]; }
        }
        // aggregates: N(0)=all-{0}/5, N(1)=all-{1}/5, N(2)=N(5)={0,1,3,4}/4,
        // N(3)=N(4)={0,1,2,5}/4
        short8 g0b, g1b, g25b, g34b, xb[NNODES];
        #pragma unroll
        for (int j = 0; j < 8; ++j) {
            const float T = xf[0][j] + xf[1][j] + xf[2][j] + xf[3][j] + xf[4][j] + xf[5][j];
            g0b[j]  = f2bf((T - xf[0][j]) * 0.2f);
            g1b[j]  = f2bf((T - xf[1][j]) * 0.2f);
            g25b[j] = f2bf((T - xf[2][j] - xf[5][j]) * 0.25f);
            g34b[j] = f2bf((T - xf[3][j] - xf[4][j]) * 0.25f);
        }
        #pragma unroll
        for (int s = 0; s < NNODES; ++s)
            #pragma unroll
            for (int j = 0; j < 8; ++j) xb[s][j] = f2bf(xf[s][j]);

        // weight fragments for this k-chunk, all 4 strips (bf16, L2-hot)
        short8 ba[4], bx[4];
        #pragma unroll
        for (int i = 0; i < 4; ++i) {
            const int o = obase + i * 16 + lo;
            ba[i] = *(const short8*)&Wb[o * KW + m * 32 + hi * 8];          // agg half (Wl)
            bx[i] = *(const short8*)&Wb[o * KW + 128 + m * 32 + hi * 8];    // x half (Wr)
        }

        #pragma unroll
        for (int i = 0; i < 4; ++i) {
            acc[0][i] = __builtin_amdgcn_mfma_f32_16x16x32_bf16(g0b,  ba[i], acc[0][i], 0, 0, 0);
            acc[1][i] = __builtin_amdgcn_mfma_f32_16x16x32_bf16(g1b,  ba[i], acc[1][i], 0, 0, 0);
            acc[2][i] = __builtin_amdgcn_mfma_f32_16x16x32_bf16(g25b, ba[i], acc[2][i], 0, 0, 0);
            acc[3][i] = __builtin_amdgcn_mfma_f32_16x16x32_bf16(g34b, ba[i], acc[3][i], 0, 0, 0);
            acc[4][i] = __builtin_amdgcn_mfma_f32_16x16x32_bf16(g34b, ba[i], acc[4][i], 0, 0, 0);
            acc[5][i] = __builtin_amdgcn_mfma_f32_16x16x32_bf16(g25b, ba[i], acc[5][i], 0, 0, 0);
            #pragma unroll
            for (int n = 0; n < NNODES; ++n)
                acc[n][i] = __builtin_amdgcn_mfma_f32_16x16x32_bf16(xb[n], bx[i], acc[n][i], 0, 0, 0);
        }
    }

    // epilogue: D col = lane&15, row = hi*4 + j (verified). tanh-GELU:
    // g = v * sigmoid(2s), s = 0.79788456*(v + 0.044715 v^3); |err| <= 1e-3
    const size_t row0 = (size_t)blockIdx.x * 16;
    #pragma unroll
    for (int n = 0; n < NNODES; ++n) {
        #pragma unroll
        for (int i = 0; i < 4; ++i) {
            const int o = obase + i * 16 + lo;
            #pragma unroll
            for (int j = 0; j < 4; ++j) {
                const float v = acc[n][i][j] + bias_v[i];
                const float s = v * (0.7978845608f + 0.0356774081f * v * v);
                const float r = __builtin_amdgcn_exp2f(-2.885390082f * s);
                const float g = v * __builtin_amdgcn_rcpf(1.0f + r);
                out[(row0 + (size_t)hi * 4 + j) * OUTW + n * 256 + o] = g;
            }
        }
    }
}

extern "C" void kernel_launch(void* const* d_in, const int* in_sizes, int n_in,
                              void* d_out, int out_size, void* d_ws, size_t ws_size,
                              hipStream_t stream) {
    const float* x  = (const float*)d_in[0];
    const float* Wl = (const float*)d_in[1];
    const float* Wr = (const float*)d_in[2];
    const float* b  = (const float*)d_in[3];
    float* out = (float*)d_out;
    short* Wb = (short*)d_ws;   // 256*256 bf16 = 128 KB

    prep_w<<<dim3(32), dim3(256), 0, stream>>>(Wl, Wr, Wb);
    sage_v3<<<dim3(NB / 16), dim3(256), 0, stream>>>(x, Wb, b, out);
}